// Round 17
// baseline (283.802 us; speedup 1.0000x reference)
//
#include <hip/hip_runtime.h>
#include <hip/hip_bf16.h>

typedef __bf16 bf16x8 __attribute__((ext_vector_type(8)));
typedef float f32x4 __attribute__((ext_vector_type(4)));
typedef unsigned short u16x8 __attribute__((ext_vector_type(8)));

static __device__ __forceinline__ unsigned short f2bf(float f){
  unsigned int u = __float_as_uint(f);
  u += 0x7fffu + ((u >> 16) & 1u);   // round-to-nearest-even
  return (unsigned short)(u >> 16);
}

static __device__ __forceinline__ u16x8 cvt8v(f32x4 a, f32x4 b){
  u16x8 r;
  #pragma unroll
  for (int e = 0; e < 4; e++) { r[e] = f2bf(a[e]); r[e+4] = f2bf(b[e]); }
  return r;
}

static __device__ __forceinline__ void gload16(const void* g, void* l){
  __builtin_amdgcn_global_load_lds(
      (const __attribute__((address_space(1))) unsigned int*)g,
      (__attribute__((address_space(3))) unsigned int*)l, 16, 0, 0);
}

// T1: XCD-aware bijective block remap (m204 variant) — r13-verified: FETCH −65%.
static __device__ __forceinline__ int xcd_remap(int o, int nwg){
  const int NX = 8;
  int q = nwg / NX, r = nwg % NX;
  int xcd = o % NX, pos = o / NX;
  return (xcd < r ? xcd * (q + 1) : r * (q + 1) + (xcd - r) * q) + pos;
}

// ---------------- pipelined bf16 GEMM (r16-verified): single barrier per K-step ------
// A:[M][K] bf16, B:[N][K] bf16, row-major. BM=BN=128, BK=32, 4 waves (2x2 of 64x64).
// 3 buffers, stage distance 2 into the buffer consumed at t-1; steady vmcnt(4).
// EPI 0: Cf = acc + bias(optional)  EPI 1: atomicAdd(Cf, acc)  EPI 2: Cbf = bf16(tanh(acc+bias))
template<int EPI>
__global__ __launch_bounds__(256) void gemm_bf(
    const unsigned short* __restrict__ A, const unsigned short* __restrict__ Bw,
    const float* __restrict__ bias,
    float* __restrict__ Cf, unsigned short* __restrict__ Cbf,
    int M, int N, int K, int kchunk)
{
  constexpr int BM = 128, BN = 128, BK = 32, BUF = (BM + BN) * BK;
  __shared__ unsigned short lds[3 * BUF];             // 3 x 16 KB

  const int gx = gridDim.x, gy = gridDim.y;
  const int nwg = gx * gy * gridDim.z;
  int o = blockIdx.x + gx * (blockIdx.y + gy * blockIdx.z);
  int v = xcd_remap(o, nwg);
  const int bx = v % gx; v /= gx;
  const int by = v % gy; const int bz = v / gy;

  const int tid  = threadIdx.x, lane = tid & 63, wave = tid >> 6;
  const int bm0  = by * BM, bn0 = bx * BN;
  const int k0   = bz * kchunk;
  const int kend = min(K, k0 + kchunk);               // kchunk multiple of 32 everywhere
  const int fr = lane & 15, fq = lane >> 4;
  const int wm = (wave >> 1) * 64, wn = (wave & 1) * 64;

  const bool isA  = wave < 2;
  const int cbase = (wave & 1) * 4;
  const int srow  = lane >> 2, scol = (lane & 3) * 8;
  const unsigned short* G = isA ? A : Bw;
  const int glim = (isA ? M : N) - 1;
  const int g0   = isA ? bm0 : bn0;
  const int loff = isA ? 0 : BM * BK;

  const int nk = (kend - k0) / BK;                    // exact (kchunk mult of 32)

  auto stage = [&](int buf, int t){
    unsigned short* dst = lds + buf * BUF + loff;
    const int kk = k0 + t * BK;
    #pragma unroll
    for (int c = 0; c < 4; c++) {
      const int ch = cbase + c;
      const int r = min(g0 + ch * 16 + srow, glim);   // clamp; epilogue masks
      gload16(G + (size_t)r * K + kk + scol, (char*)dst + ch * 1024);
    }
  };

  if (nk > 0) stage(0, 0);
  if (nk > 1) stage(1, 1);

  f32x4 acc[4][4] = {};
  int cur = 0;                                        // = t % 3

  for (int t = 0; t < nk; ++t) {
    if (t < nk - 1) asm volatile("s_waitcnt vmcnt(4)" ::: "memory");
    else            asm volatile("s_waitcnt vmcnt(0)" ::: "memory");
    __builtin_amdgcn_s_barrier();                     // tile t fully landed; t-1 reads done
    __builtin_amdgcn_sched_barrier(0);

    if (t + 2 < nk) {                                 // refill buffer freed at t-1
      int sb = cur + 2; if (sb >= 3) sb -= 3;         // (t+2) % 3
      stage(sb, t + 2);
    }

    const unsigned short* lA = lds + cur * BUF;
    const unsigned short* lB = lA + BM * BK;
    u16x8 af[4], bg[4];
    #pragma unroll
    for (int i = 0; i < 4; i++) af[i] = *(const u16x8*)&lA[(wm + i*16 + fr) * BK + fq * 8];
    #pragma unroll
    for (int j = 0; j < 4; j++) bg[j] = *(const u16x8*)&lB[(wn + j*16 + fr) * BK + fq * 8];

    #pragma unroll
    for (int i = 0; i < 4; i++)
      #pragma unroll
      for (int j = 0; j < 4; j++)
        acc[i][j] = __builtin_amdgcn_mfma_f32_16x16x32_bf16(
            __builtin_bit_cast(bf16x8, af[i]),
            __builtin_bit_cast(bf16x8, bg[j]),
            acc[i][j], 0, 0, 0);
    cur = (cur == 2) ? 0 : cur + 1;
  }

  #pragma unroll
  for (int i = 0; i < 4; i++)
    #pragma unroll
    for (int j = 0; j < 4; j++)
      #pragma unroll
      for (int r = 0; r < 4; r++) {
        int row = bm0 + wm + i*16 + fq*4 + r;
        int col = bn0 + wn + j*16 + fr;
        if (row < M && col < N) {
          float v2 = acc[i][j][r];
          if constexpr (EPI == 0) {
            Cf[(size_t)row * N + col] = v2 + (bias ? bias[col] : 0.0f);
          } else if constexpr (EPI == 1) {
            atomicAdd(&Cf[(size_t)row * N + col], v2);
          } else {
            Cbf[(size_t)row * N + col] = f2bf(tanhf(v2 + bias[col]));
          }
        }
      }
}

// ---------- cvtpad helper: fp32 [rows][scols] -> bf16 [rows][dcols], zero-padded ------
// NT loads: source fp32 is read-once, don't allocate it in L2/L3.
static __device__ __forceinline__ void cvtpad_body(
    const float* __restrict__ src, unsigned short* __restrict__ dst,
    int rows, int scols, int dcols, int i8)
{
  int c8 = dcols / 8;
  if (i8 >= rows * c8) return;
  int r = i8 / c8, c0 = (i8 % c8) * 8;
  const float* s = src + (size_t)r * scols;
  u16x8 o;
  #pragma unroll
  for (int e = 0; e < 8; e++) {
    int c = c0 + e;
    o[e] = (c < scols) ? f2bf(__builtin_nontemporal_load(s + c)) : (unsigned short)0;
  }
  *(u16x8*)(dst + (size_t)r * dcols + c0) = o;
}

// ---------- merged prep: cvt4 (weights->bf16) ∥ ynorm ∥ cvtpad(embed) ∥ cvtpad(Wi) ----
// r17 change: ALL fp32 source reads are NON-TEMPORAL. Every input stream here is
// read-once per launch; allocating them in L2/L3 evicts the buffers the GEMMs re-read
// (y, We1b, Wd2b). L3 is at capacity (prep FETCH=130MB vs 263MB logical => ~50% thrash).
__global__ __launch_bounds__(256) void prep_kernel(
    const float* __restrict__ We1, unsigned short* __restrict__ We1b,
    const float* __restrict__ Wd2, unsigned short* __restrict__ Wd2b,
    const float* __restrict__ We2, unsigned short* __restrict__ We2b,
    const float* __restrict__ Wd1, unsigned short* __restrict__ Wd1b,
    const float* __restrict__ embed, unsigned short* __restrict__ embedb,
    const float* __restrict__ Wi, unsigned short* __restrict__ Wib,
    const float* __restrict__ x, const float* __restrict__ dm,
    unsigned short* __restrict__ y, float* __restrict__ ninv)
{
  constexpr int D0 = 20000, H = 1024, L = 256, V = 3356, E = 1128, Ep = 1152;
  constexpr int n0 = H * D0, n1 = D0 * H, n2 = 2 * L * H, n3 = H * L;
  constexpr int CVT_B = 2048, YN_B = 512;
  constexpr int PE_B = (V * (Ep / 8) + 255) / 256;     // 1888
  const int bb = blockIdx.x, tid = threadIdx.x;

  if (bb < CVT_B) {
    constexpr int nunits16 = (n0 + n1 + n2 + n3) / 16;
    const int stride = CVT_B * 256;
    for (int u = bb * 256 + tid; u < nunits16; u += stride) {
      int i = u * 16;
      const float* s; unsigned short* d;
      if (i < n0)              { s = We1; d = We1b; }
      else if ((i -= n0) < n1) { s = Wd2; d = Wd2b; }
      else if ((i -= n1) < n2) { s = We2; d = We2b; }
      else                     { i -= n2; s = Wd1; d = Wd1b; }
      const f32x4* q = (const f32x4*)(s + i);
      f32x4 a0 = __builtin_nontemporal_load(q);
      f32x4 a1 = __builtin_nontemporal_load(q + 1);
      f32x4 a2 = __builtin_nontemporal_load(q + 2);
      f32x4 a3 = __builtin_nontemporal_load(q + 3);
      *(u16x8*)(d + i)     = cvt8v(a0, a1);
      *(u16x8*)(d + i + 8) = cvt8v(a2, a3);
    }
  } else if (bb < CVT_B + YN_B) {
    const int b = bb - CVT_B;
    const f32x4* x4 = (const f32x4*)(x + (size_t)b * D0);
    const f32x4* d4 = (const f32x4*)(dm + (size_t)b * D0);
    ushort4* y4 = (ushort4*)(y + (size_t)b * D0);
    const int n4 = D0 / 4;
    float ss = 0.f;
    for (int i = tid; i < n4; i += 256) {
      f32x4 xv = __builtin_nontemporal_load(x4 + i);
      f32x4 dv = __builtin_nontemporal_load(d4 + i);
      ss += xv[0]*xv[0] + xv[1]*xv[1] + xv[2]*xv[2] + xv[3]*xv[3];
      ushort4 ov;
      ov.x = f2bf(xv[0]*dv[0]); ov.y = f2bf(xv[1]*dv[1]);
      ov.z = f2bf(xv[2]*dv[2]); ov.w = f2bf(xv[3]*dv[3]);
      y4[i] = ov;
    }
    #pragma unroll
    for (int off = 32; off > 0; off >>= 1) ss += __shfl_down(ss, off);
    __shared__ float wsum[4];
    if ((tid & 63) == 0) wsum[tid >> 6] = ss;
    __syncthreads();
    if (tid == 0) {
      float t = wsum[0] + wsum[1] + wsum[2] + wsum[3];
      ninv[b] = 1.0f / fmaxf(sqrtf(t), 1e-12f);
    }
  } else if (bb < CVT_B + YN_B + PE_B) {
    cvtpad_body(embed, embedb, V, E, Ep, (bb - (CVT_B + YN_B)) * 256 + tid);
  } else {
    cvtpad_body(Wi, Wib, L, E, Ep, (bb - (CVT_B + YN_B + PE_B)) * 256 + tid);
  }
}

// ---------------- remaining elementwise / reduction kernels ----------------
__global__ __launch_bounds__(256) void stats_kernel(
    const float* __restrict__ proj, const int* __restrict__ ids,
    const float* __restrict__ bi, const float* __restrict__ eps,
    float* __restrict__ prior, int T)
{
  const int b = blockIdx.x, l = threadIdx.x;
  __shared__ int sid[256];
  if (l < T) sid[l] = ids[b * T + l];
  __syncthreads();
  float s1 = 0.f, s2 = 0.f;
  #pragma unroll 4
  for (int t = 0; t < T; t++) {
    float p = proj[(size_t)sid[t] * 256 + l];
    s1 += p; s2 += p * p;
  }
  float var = fmaxf((s2 - s1 * s1 / (float)T) / (float)(T - 1), 0.f);
  float dev = sqrtf(var);
  float mean = s1 / (float)T + bi[l];
  prior[b * 256 + l] = mean + sqrtf(dev) * eps[b * 256 + l];
}

__global__ __launch_bounds__(256) void epi1_kernel(
    const float* __restrict__ C1, const float* __restrict__ ninv,
    const float* __restrict__ be1, unsigned short* __restrict__ h)
{
  int i = blockIdx.x * 256 + threadIdx.x;
  int b = i >> 10, n = i & 1023;
  h[i] = f2bf(tanhf(ninv[b] * C1[i] + be1[n]));
}

__global__ __launch_bounds__(256) void z_kernel(
    const float* __restrict__ gp, const float* __restrict__ prior,
    const float* __restrict__ be2,
    float* __restrict__ out_mu, float* __restrict__ out_lv,
    unsigned short* __restrict__ z)
{
  int i = blockIdx.x * 256 + threadIdx.x;
  int b = i >> 8, l = i & 255;
  float mu = gp[b * 512 + l]       + be2[l];
  float lv = gp[b * 512 + 256 + l] + be2[256 + l];
  out_mu[i] = mu;
  out_lv[i] = lv;
  z[i] = f2bf(prior[i] * expf(0.5f * lv) + mu);
}

extern "C" void kernel_launch(void* const* d_in, const int* in_sizes, int n_in,
                              void* d_out, int out_size, void* d_ws, size_t ws_size,
                              hipStream_t stream)
{
  const float* x     = (const float*)d_in[0];
  const int*   ids   = (const int*)  d_in[1];
  const float* embed = (const float*)d_in[2];
  const float* Wi    = (const float*)d_in[3];
  const float* bi    = (const float*)d_in[4];
  const float* We1   = (const float*)d_in[5];
  const float* be1   = (const float*)d_in[6];
  const float* We2   = (const float*)d_in[7];
  const float* be2   = (const float*)d_in[8];
  const float* Wd1   = (const float*)d_in[9];
  const float* bd1   = (const float*)d_in[10];
  const float* Wd2   = (const float*)d_in[11];
  const float* bd2   = (const float*)d_in[12];
  const float* dm    = (const float*)d_in[13];
  const float* eps   = (const float*)d_in[14];

  constexpr int B = 512, T = 200, V = 3356, E = 1128, Ep = 1152, D0 = 20000, H = 1024, L = 256;

  char* w = (char*)d_ws;
  auto carve = [&](size_t bytes) { char* p = w; w += (bytes + 255) & ~(size_t)255; return p; };
  unsigned short* We1b  = (unsigned short*)carve((size_t)H * D0 * 2);   // 41 MB
  unsigned short* Wd2b  = (unsigned short*)carve((size_t)D0 * H * 2);   // 41 MB
  unsigned short* We2b  = (unsigned short*)carve((size_t)2 * L * H * 2);
  unsigned short* Wd1b  = (unsigned short*)carve((size_t)H * L * 2);
  unsigned short* embedb= (unsigned short*)carve((size_t)V * Ep * 2);   // 7.7 MB
  unsigned short* Wib   = (unsigned short*)carve((size_t)L * Ep * 2);
  float*          proj  = (float*)         carve((size_t)V * L * 4);    // 3.4 MB
  unsigned short* y     = (unsigned short*)carve((size_t)B * D0 * 2);   // 20.5 MB
  float*          C1    = (float*)         carve((size_t)B * H * 4);
  unsigned short* h     = (unsigned short*)carve((size_t)B * H * 2);
  float*          gp    = (float*)         carve((size_t)B * 2 * L * 4);
  float*          prior = (float*)         carve((size_t)B * L * 4);
  unsigned short* z     = (unsigned short*)carve((size_t)B * L * 2);
  unsigned short* hd    = (unsigned short*)carve((size_t)B * H * 2);
  float*          ninv  = (float*)         carve((size_t)B * 4);

  float* out_recon = (float*)d_out;
  float* out_mu    = out_recon + (size_t)B * D0;
  float* out_lv    = out_mu + (size_t)B * L;

  // merged prep: weights->bf16 ∥ y=bf16(x*dm)+ninv ∥ embed/Wi pad-convert (NT loads)
  {
    constexpr int CVT_B = 2048, YN_B = 512;
    constexpr int PE_B = (V * (Ep / 8) + 255) / 256;    // 1888
    constexpr int PW_B = (L * (Ep / 8) + 255) / 256;    // 144
    prep_kernel<<<CVT_B + YN_B + PE_B + PW_B, 256, 0, stream>>>(
        We1, We1b, Wd2, Wd2b, We2, We2b, Wd1, Wd1b,
        embed, embedb, Wi, Wib, x, dm, y, ninv);
  }

  // proj = embedb @ Wib^T  (M=3356, N=256, K=1152), split-K=4
  hipMemsetAsync(proj, 0, (size_t)V * L * 4, stream);
  gemm_bf<1><<<dim3(2, 27, 4), 256, 0, stream>>>(
      embedb, Wib, nullptr, proj, nullptr, V, L, Ep, 288);
  // prior from gathered stats (adds bi)
  stats_kernel<<<B, 256, 0, stream>>>(proj, ids, bi, eps, prior, T);

  // GEMM1: C1 = y @ We1b^T  (M=512, N=1024, K=20000), split-K=25
  hipMemsetAsync(C1, 0, (size_t)B * H * 4, stream);
  gemm_bf<1><<<dim3(8, 4, 25), 256, 0, stream>>>(
      y, We1b, nullptr, C1, nullptr, B, H, D0, 800);
  // h = tanh(ninv*C1 + be1)
  epi1_kernel<<<(B * H) / 256, 256, 0, stream>>>(C1, ninv, be1, h);

  // gparams = h @ We2b^T (+be2 in z_kernel)  (M=512, N=512, K=1024), split-K=4
  hipMemsetAsync(gp, 0, (size_t)B * 2 * L * 4, stream);
  gemm_bf<1><<<dim3(4, 4, 4), 256, 0, stream>>>(
      h, We2b, nullptr, gp, nullptr, B, 2 * L, H, 256);
  // mu/logvar out, z
  z_kernel<<<(B * L) / 256, 256, 0, stream>>>(gp, prior, be2, out_mu, out_lv, z);

  // hd = tanh(z @ Wd1b^T + bd1)  (M=512, N=1024, K=256)
  gemm_bf<2><<<dim3(8, 4, 1), 256, 0, stream>>>(
      z, Wd1b, bd1, nullptr, hd, B, H, L, 256);
  // recon = hd @ Wd2b^T + bd2   (M=512, N=20000, K=1024)
  gemm_bf<0><<<dim3(157, 4, 1), 256, 0, stream>>>(
      hd, Wd2b, bd2, out_recon, nullptr, B, D0, H, 1024);
}

// Round 18
// 259.463 us; speedup vs baseline: 1.0938x; 1.0938x over previous
//
#include <hip/hip_runtime.h>
#include <hip/hip_bf16.h>

typedef __bf16 bf16x8 __attribute__((ext_vector_type(8)));
typedef float f32x4 __attribute__((ext_vector_type(4)));
typedef unsigned short u16x8 __attribute__((ext_vector_type(8)));

static __device__ __forceinline__ unsigned short f2bf(float f){
  unsigned int u = __float_as_uint(f);
  u += 0x7fffu + ((u >> 16) & 1u);   // round-to-nearest-even
  return (unsigned short)(u >> 16);
}

static __device__ __forceinline__ u16x8 cvt8(const float4& a, const float4& b){
  u16x8 r;
  r[0]=f2bf(a.x); r[1]=f2bf(a.y); r[2]=f2bf(a.z); r[3]=f2bf(a.w);
  r[4]=f2bf(b.x); r[5]=f2bf(b.y); r[6]=f2bf(b.z); r[7]=f2bf(b.w);
  return r;
}

static __device__ __forceinline__ void gload16(const void* g, void* l){
  __builtin_amdgcn_global_load_lds(
      (const __attribute__((address_space(1))) unsigned int*)g,
      (__attribute__((address_space(3))) unsigned int*)l, 16, 0, 0);
}

// T1: XCD-aware bijective block remap (m204 variant) — r13-verified: FETCH −65%.
static __device__ __forceinline__ int xcd_remap(int o, int nwg){
  const int NX = 8;
  int q = nwg / NX, r = nwg % NX;
  int xcd = o % NX, pos = o / NX;
  return (xcd < r ? xcd * (q + 1) : r * (q + 1) + (xcd - r) * q) + pos;
}

// ---------------- pipelined bf16 GEMM (r16-verified): single barrier per K-step ------
// A:[M][K] bf16, B:[N][K] bf16, row-major. BM=BN=128, BK=32, 4 waves (2x2 of 64x64).
// 3 buffers, stage distance 2 into the buffer consumed at t-1; steady vmcnt(4).
// Safety: top-of-iter vmcnt(4) [own tile-t loads landed] -> s_barrier [all waves
// likewise, and all waves' t-1 frag reads complete] -> staging into t-1's buffer safe.
// EPI 0: Cf = acc + bias(optional)  EPI 1: atomicAdd(Cf, acc)  EPI 2: Cbf = bf16(tanh(acc+bias))
template<int EPI>
__global__ __launch_bounds__(256) void gemm_bf(
    const unsigned short* __restrict__ A, const unsigned short* __restrict__ Bw,
    const float* __restrict__ bias,
    float* __restrict__ Cf, unsigned short* __restrict__ Cbf,
    int M, int N, int K, int kchunk)
{
  constexpr int BM = 128, BN = 128, BK = 32, BUF = (BM + BN) * BK;
  __shared__ unsigned short lds[3 * BUF];             // 3 x 16 KB

  const int gx = gridDim.x, gy = gridDim.y;
  const int nwg = gx * gy * gridDim.z;
  int o = blockIdx.x + gx * (blockIdx.y + gy * blockIdx.z);
  int v = xcd_remap(o, nwg);
  const int bx = v % gx; v /= gx;
  const int by = v % gy; const int bz = v / gy;

  const int tid  = threadIdx.x, lane = tid & 63, wave = tid >> 6;
  const int bm0  = by * BM, bn0 = bx * BN;
  const int k0   = bz * kchunk;
  const int kend = min(K, k0 + kchunk);               // kchunk multiple of 32 everywhere
  const int fr = lane & 15, fq = lane >> 4;
  const int wm = (wave >> 1) * 64, wn = (wave & 1) * 64;

  const bool isA  = wave < 2;
  const int cbase = (wave & 1) * 4;
  const int srow  = lane >> 2, scol = (lane & 3) * 8;
  const unsigned short* G = isA ? A : Bw;
  const int glim = (isA ? M : N) - 1;
  const int g0   = isA ? bm0 : bn0;
  const int loff = isA ? 0 : BM * BK;

  const int nk = (kend - k0) / BK;                    // exact (kchunk mult of 32)

  auto stage = [&](int buf, int t){
    unsigned short* dst = lds + buf * BUF + loff;
    const int kk = k0 + t * BK;
    #pragma unroll
    for (int c = 0; c < 4; c++) {
      const int ch = cbase + c;
      const int r = min(g0 + ch * 16 + srow, glim);   // clamp; epilogue masks
      gload16(G + (size_t)r * K + kk + scol, (char*)dst + ch * 1024);
    }
  };

  if (nk > 0) stage(0, 0);
  if (nk > 1) stage(1, 1);

  f32x4 acc[4][4] = {};
  int cur = 0;                                        // = t % 3

  for (int t = 0; t < nk; ++t) {
    if (t < nk - 1) asm volatile("s_waitcnt vmcnt(4)" ::: "memory");
    else            asm volatile("s_waitcnt vmcnt(0)" ::: "memory");
    __builtin_amdgcn_s_barrier();                     // tile t fully landed; t-1 reads done
    __builtin_amdgcn_sched_barrier(0);

    if (t + 2 < nk) {                                 // refill buffer freed at t-1
      int sb = cur + 2; if (sb >= 3) sb -= 3;         // (t+2) % 3
      stage(sb, t + 2);
    }

    const unsigned short* lA = lds + cur * BUF;
    const unsigned short* lB = lA + BM * BK;
    u16x8 af[4], bg[4];
    #pragma unroll
    for (int i = 0; i < 4; i++) af[i] = *(const u16x8*)&lA[(wm + i*16 + fr) * BK + fq * 8];
    #pragma unroll
    for (int j = 0; j < 4; j++) bg[j] = *(const u16x8*)&lB[(wn + j*16 + fr) * BK + fq * 8];

    #pragma unroll
    for (int i = 0; i < 4; i++)
      #pragma unroll
      for (int j = 0; j < 4; j++)
        acc[i][j] = __builtin_amdgcn_mfma_f32_16x16x32_bf16(
            __builtin_bit_cast(bf16x8, af[i]),
            __builtin_bit_cast(bf16x8, bg[j]),
            acc[i][j], 0, 0, 0);
    cur = (cur == 2) ? 0 : cur + 1;
  }

  #pragma unroll
  for (int i = 0; i < 4; i++)
    #pragma unroll
    for (int j = 0; j < 4; j++)
      #pragma unroll
      for (int r = 0; r < 4; r++) {
        int row = bm0 + wm + i*16 + fq*4 + r;
        int col = bn0 + wn + j*16 + fr;
        if (row < M && col < N) {
          float v2 = acc[i][j][r];
          if constexpr (EPI == 0) {
            Cf[(size_t)row * N + col] = v2 + (bias ? bias[col] : 0.0f);
          } else if constexpr (EPI == 1) {
            atomicAdd(&Cf[(size_t)row * N + col], v2);
          } else {
            Cbf[(size_t)row * N + col] = f2bf(tanhf(v2 + bias[col]));
          }
        }
      }
}

// ---------- cvtpad helper: fp32 [rows][scols] -> bf16 [rows][dcols], zero-padded ------
static __device__ __forceinline__ void cvtpad_body(
    const float* __restrict__ src, unsigned short* __restrict__ dst,
    int rows, int scols, int dcols, int i8)
{
  int c8 = dcols / 8;
  if (i8 >= rows * c8) return;
  int r = i8 / c8, c0 = (i8 % c8) * 8;
  const float* s = src + (size_t)r * scols;
  u16x8 o;
  #pragma unroll
  for (int e = 0; e < 8; e++) { int c = c0 + e; o[e] = (c < scols) ? f2bf(s[c]) : (unsigned short)0; }
  *(u16x8*)(dst + (size_t)r * dcols + c0) = o;
}

// ---------- merged prep: cvt4 (weights->bf16) ∥ ynorm ∥ cvtpad(embed) ∥ cvtpad(Wi) ----
// One dispatch; block ranges take different roles (r16-verified: overlap beats serial).
// Normal (cached) loads — r17 proved NT loads regress (L3 absorbs replay re-reads).
__global__ __launch_bounds__(256) void prep_kernel(
    const float* __restrict__ We1, unsigned short* __restrict__ We1b,
    const float* __restrict__ Wd2, unsigned short* __restrict__ Wd2b,
    const float* __restrict__ We2, unsigned short* __restrict__ We2b,
    const float* __restrict__ Wd1, unsigned short* __restrict__ Wd1b,
    const float* __restrict__ embed, unsigned short* __restrict__ embedb,
    const float* __restrict__ Wi, unsigned short* __restrict__ Wib,
    const float* __restrict__ x, const float* __restrict__ dm,
    unsigned short* __restrict__ y, float* __restrict__ ninv)
{
  constexpr int D0 = 20000, H = 1024, L = 256, V = 3356, E = 1128, Ep = 1152;
  constexpr int n0 = H * D0, n1 = D0 * H, n2 = 2 * L * H, n3 = H * L;
  constexpr int CVT_B = 2048, YN_B = 512;
  constexpr int PE_B = (V * (Ep / 8) + 255) / 256;     // 1888
  const int bb = blockIdx.x, tid = threadIdx.x;

  if (bb < CVT_B) {
    constexpr int nunits16 = (n0 + n1 + n2 + n3) / 16;
    const int stride = CVT_B * 256;
    for (int u = bb * 256 + tid; u < nunits16; u += stride) {
      int i = u * 16;
      const float* s; unsigned short* d;
      if (i < n0)              { s = We1; d = We1b; }
      else if ((i -= n0) < n1) { s = Wd2; d = Wd2b; }
      else if ((i -= n1) < n2) { s = We2; d = We2b; }
      else                     { i -= n2; s = Wd1; d = Wd1b; }
      const float4* q = (const float4*)(s + i);
      float4 a0 = q[0], a1 = q[1], a2 = q[2], a3 = q[3];
      *(u16x8*)(d + i)     = cvt8(a0, a1);
      *(u16x8*)(d + i + 8) = cvt8(a2, a3);
    }
  } else if (bb < CVT_B + YN_B) {
    const int b = bb - CVT_B;
    const float4* x4 = (const float4*)(x + (size_t)b * D0);
    const float4* d4 = (const float4*)(dm + (size_t)b * D0);
    ushort4* y4 = (ushort4*)(y + (size_t)b * D0);
    const int n4 = D0 / 4;
    float ss = 0.f;
    for (int i = tid; i < n4; i += 256) {
      float4 xv = x4[i], dv = d4[i];
      ss += xv.x*xv.x + xv.y*xv.y + xv.z*xv.z + xv.w*xv.w;
      ushort4 ov;
      ov.x = f2bf(xv.x*dv.x); ov.y = f2bf(xv.y*dv.y);
      ov.z = f2bf(xv.z*dv.z); ov.w = f2bf(xv.w*dv.w);
      y4[i] = ov;
    }
    #pragma unroll
    for (int off = 32; off > 0; off >>= 1) ss += __shfl_down(ss, off);
    __shared__ float wsum[4];
    if ((tid & 63) == 0) wsum[tid >> 6] = ss;
    __syncthreads();
    if (tid == 0) {
      float t = wsum[0] + wsum[1] + wsum[2] + wsum[3];
      ninv[b] = 1.0f / fmaxf(sqrtf(t), 1e-12f);
    }
  } else if (bb < CVT_B + YN_B + PE_B) {
    cvtpad_body(embed, embedb, V, E, Ep, (bb - (CVT_B + YN_B)) * 256 + tid);
  } else {
    cvtpad_body(Wi, Wib, L, E, Ep, (bb - (CVT_B + YN_B + PE_B)) * 256 + tid);
  }
}

// ---------------- remaining elementwise / reduction kernels ----------------
__global__ __launch_bounds__(256) void stats_kernel(
    const float* __restrict__ proj, const int* __restrict__ ids,
    const float* __restrict__ bi, const float* __restrict__ eps,
    float* __restrict__ prior, int T)
{
  const int b = blockIdx.x, l = threadIdx.x;
  __shared__ int sid[256];
  if (l < T) sid[l] = ids[b * T + l];
  __syncthreads();
  float s1 = 0.f, s2 = 0.f;
  #pragma unroll 4
  for (int t = 0; t < T; t++) {
    float p = proj[(size_t)sid[t] * 256 + l];
    s1 += p; s2 += p * p;
  }
  float var = fmaxf((s2 - s1 * s1 / (float)T) / (float)(T - 1), 0.f);
  float dev = sqrtf(var);
  float mean = s1 / (float)T + bi[l];
  prior[b * 256 + l] = mean + sqrtf(dev) * eps[b * 256 + l];
}

__global__ __launch_bounds__(256) void epi1_kernel(
    const float* __restrict__ C1, const float* __restrict__ ninv,
    const float* __restrict__ be1, unsigned short* __restrict__ h)
{
  int i = blockIdx.x * 256 + threadIdx.x;
  int b = i >> 10, n = i & 1023;
  h[i] = f2bf(tanhf(ninv[b] * C1[i] + be1[n]));
}

__global__ __launch_bounds__(256) void z_kernel(
    const float* __restrict__ gp, const float* __restrict__ prior,
    const float* __restrict__ be2,
    float* __restrict__ out_mu, float* __restrict__ out_lv,
    unsigned short* __restrict__ z)
{
  int i = blockIdx.x * 256 + threadIdx.x;
  int b = i >> 8, l = i & 255;
  float mu = gp[b * 512 + l]       + be2[l];
  float lv = gp[b * 512 + 256 + l] + be2[256 + l];
  out_mu[i] = mu;
  out_lv[i] = lv;
  z[i] = f2bf(prior[i] * expf(0.5f * lv) + mu);
}

extern "C" void kernel_launch(void* const* d_in, const int* in_sizes, int n_in,
                              void* d_out, int out_size, void* d_ws, size_t ws_size,
                              hipStream_t stream)
{
  const float* x     = (const float*)d_in[0];
  const int*   ids   = (const int*)  d_in[1];
  const float* embed = (const float*)d_in[2];
  const float* Wi    = (const float*)d_in[3];
  const float* bi    = (const float*)d_in[4];
  const float* We1   = (const float*)d_in[5];
  const float* be1   = (const float*)d_in[6];
  const float* We2   = (const float*)d_in[7];
  const float* be2   = (const float*)d_in[8];
  const float* Wd1   = (const float*)d_in[9];
  const float* bd1   = (const float*)d_in[10];
  const float* Wd2   = (const float*)d_in[11];
  const float* bd2   = (const float*)d_in[12];
  const float* dm    = (const float*)d_in[13];
  const float* eps   = (const float*)d_in[14];

  constexpr int B = 512, T = 200, V = 3356, E = 1128, Ep = 1152, D0 = 20000, H = 1024, L = 256;

  char* w = (char*)d_ws;
  auto carve = [&](size_t bytes) { char* p = w; w += (bytes + 255) & ~(size_t)255; return p; };
  unsigned short* We1b  = (unsigned short*)carve((size_t)H * D0 * 2);   // 41 MB
  unsigned short* Wd2b  = (unsigned short*)carve((size_t)D0 * H * 2);   // 41 MB
  unsigned short* We2b  = (unsigned short*)carve((size_t)2 * L * H * 2);
  unsigned short* Wd1b  = (unsigned short*)carve((size_t)H * L * 2);
  unsigned short* embedb= (unsigned short*)carve((size_t)V * Ep * 2);   // 7.7 MB
  unsigned short* Wib   = (unsigned short*)carve((size_t)L * Ep * 2);
  float*          proj  = (float*)         carve((size_t)V * L * 4);    // 3.4 MB
  unsigned short* y     = (unsigned short*)carve((size_t)B * D0 * 2);   // 20.5 MB
  float*          C1    = (float*)         carve((size_t)B * H * 4);
  unsigned short* h     = (unsigned short*)carve((size_t)B * H * 2);
  float*          gp    = (float*)         carve((size_t)B * 2 * L * 4);
  float*          prior = (float*)         carve((size_t)B * L * 4);
  unsigned short* z     = (unsigned short*)carve((size_t)B * L * 2);
  unsigned short* hd    = (unsigned short*)carve((size_t)B * H * 2);
  float*          ninv  = (float*)         carve((size_t)B * 4);

  float* out_recon = (float*)d_out;
  float* out_mu    = out_recon + (size_t)B * D0;
  float* out_lv    = out_mu + (size_t)B * L;

  // merged prep: weights->bf16 ∥ y=bf16(x*dm)+ninv ∥ embed/Wi pad-convert
  {
    constexpr int CVT_B = 2048, YN_B = 512;
    constexpr int PE_B = (V * (Ep / 8) + 255) / 256;    // 1888
    constexpr int PW_B = (L * (Ep / 8) + 255) / 256;    // 144
    prep_kernel<<<CVT_B + YN_B + PE_B + PW_B, 256, 0, stream>>>(
        We1, We1b, Wd2, Wd2b, We2, We2b, Wd1, Wd1b,
        embed, embedb, Wi, Wib, x, dm, y, ninv);
  }

  // proj = embedb @ Wib^T  (M=3356, N=256, K=1152), split-K=4
  hipMemsetAsync(proj, 0, (size_t)V * L * 4, stream);
  gemm_bf<1><<<dim3(2, 27, 4), 256, 0, stream>>>(
      embedb, Wib, nullptr, proj, nullptr, V, L, Ep, 288);
  // prior from gathered stats (adds bi)
  stats_kernel<<<B, 256, 0, stream>>>(proj, ids, bi, eps, prior, T);

  // GEMM1: C1 = y @ We1b^T  (M=512, N=1024, K=20000), split-K=25
  hipMemsetAsync(C1, 0, (size_t)B * H * 4, stream);
  gemm_bf<1><<<dim3(8, 4, 25), 256, 0, stream>>>(
      y, We1b, nullptr, C1, nullptr, B, H, D0, 800);
  // h = tanh(ninv*C1 + be1)
  epi1_kernel<<<(B * H) / 256, 256, 0, stream>>>(C1, ninv, be1, h);

  // gparams = h @ We2b^T (+be2 in z_kernel)  (M=512, N=512, K=1024), split-K=4
  hipMemsetAsync(gp, 0, (size_t)B * 2 * L * 4, stream);
  gemm_bf<1><<<dim3(4, 4, 4), 256, 0, stream>>>(
      h, We2b, nullptr, gp, nullptr, B, 2 * L, H, 256);
  // mu/logvar out, z
  z_kernel<<<(B * L) / 256, 256, 0, stream>>>(gp, prior, be2, out_mu, out_lv, z);

  // hd = tanh(z @ Wd1b^T + bd1)  (M=512, N=1024, K=256)
  gemm_bf<2><<<dim3(8, 4, 1), 256, 0, stream>>>(
      z, Wd1b, bd1, nullptr, hd, B, H, L, 256);
  // recon = hd @ Wd2b^T + bd2   (M=512, N=20000, K=1024)
  gemm_bf<0><<<dim3(157, 4, 1), 256, 0, stream>>>(
      hd, Wd2b, bd2, out_recon, nullptr, B, D0, H, 1024);
}

// Round 19
// 257.422 us; speedup vs baseline: 1.1025x; 1.0079x over previous
//
#include <hip/hip_runtime.h>
#include <hip/hip_bf16.h>

typedef __bf16 bf16x8 __attribute__((ext_vector_type(8)));
typedef float f32x4 __attribute__((ext_vector_type(4)));
typedef unsigned short u16x8 __attribute__((ext_vector_type(8)));

static __device__ __forceinline__ unsigned short f2bf(float f){
  unsigned int u = __float_as_uint(f);
  u += 0x7fffu + ((u >> 16) & 1u);   // round-to-nearest-even
  return (unsigned short)(u >> 16);
}

static __device__ __forceinline__ u16x8 cvt8(const float4& a, const float4& b){
  u16x8 r;
  r[0]=f2bf(a.x); r[1]=f2bf(a.y); r[2]=f2bf(a.z); r[3]=f2bf(a.w);
  r[4]=f2bf(b.x); r[5]=f2bf(b.y); r[6]=f2bf(b.z); r[7]=f2bf(b.w);
  return r;
}

static __device__ __forceinline__ ushort4 cvt4h(f32x4 a){
  ushort4 r;
  r.x = f2bf(a[0]); r.y = f2bf(a[1]); r.z = f2bf(a[2]); r.w = f2bf(a[3]);
  return r;
}

static __device__ __forceinline__ void gload16(const void* g, void* l){
  __builtin_amdgcn_global_load_lds(
      (const __attribute__((address_space(1))) unsigned int*)g,
      (__attribute__((address_space(3))) unsigned int*)l, 16, 0, 0);
}

// T1: XCD-aware bijective block remap (m204 variant) — r13-verified: FETCH −65%.
static __device__ __forceinline__ int xcd_remap(int o, int nwg){
  const int NX = 8;
  int q = nwg / NX, r = nwg % NX;
  int xcd = o % NX, pos = o / NX;
  return (xcd < r ? xcd * (q + 1) : r * (q + 1) + (xcd - r) * q) + pos;
}

// ---------------- pipelined bf16 GEMM (r16-verified): single barrier per K-step ------
// A:[M][K] bf16, B:[N][K] bf16, row-major. BM=BN=128, BK=32, 4 waves (2x2 of 64x64).
// 3 buffers, stage distance 2 into the buffer consumed at t-1; steady vmcnt(4).
// EPI 0: Cf = acc + bias(optional)  EPI 1: atomicAdd(Cf, acc)  EPI 2: Cbf = bf16(tanh(acc+bias))
template<int EPI>
__global__ __launch_bounds__(256) void gemm_bf(
    const unsigned short* __restrict__ A, const unsigned short* __restrict__ Bw,
    const float* __restrict__ bias,
    float* __restrict__ Cf, unsigned short* __restrict__ Cbf,
    int M, int N, int K, int kchunk)
{
  constexpr int BM = 128, BN = 128, BK = 32, BUF = (BM + BN) * BK;
  __shared__ unsigned short lds[3 * BUF];             // 3 x 16 KB

  const int gx = gridDim.x, gy = gridDim.y;
  const int nwg = gx * gy * gridDim.z;
  int o = blockIdx.x + gx * (blockIdx.y + gy * blockIdx.z);
  int v = xcd_remap(o, nwg);
  const int bx = v % gx; v /= gx;
  const int by = v % gy; const int bz = v / gy;

  const int tid  = threadIdx.x, lane = tid & 63, wave = tid >> 6;
  const int bm0  = by * BM, bn0 = bx * BN;
  const int k0   = bz * kchunk;
  const int kend = min(K, k0 + kchunk);               // kchunk multiple of 32 everywhere
  const int fr = lane & 15, fq = lane >> 4;
  const int wm = (wave >> 1) * 64, wn = (wave & 1) * 64;

  const bool isA  = wave < 2;
  const int cbase = (wave & 1) * 4;
  const int srow  = lane >> 2, scol = (lane & 3) * 8;
  const unsigned short* G = isA ? A : Bw;
  const int glim = (isA ? M : N) - 1;
  const int g0   = isA ? bm0 : bn0;
  const int loff = isA ? 0 : BM * BK;

  const int nk = (kend - k0) / BK;                    // exact (kchunk mult of 32)

  auto stage = [&](int buf, int t){
    unsigned short* dst = lds + buf * BUF + loff;
    const int kk = k0 + t * BK;
    #pragma unroll
    for (int c = 0; c < 4; c++) {
      const int ch = cbase + c;
      const int r = min(g0 + ch * 16 + srow, glim);   // clamp; epilogue masks
      gload16(G + (size_t)r * K + kk + scol, (char*)dst + ch * 1024);
    }
  };

  if (nk > 0) stage(0, 0);
  if (nk > 1) stage(1, 1);

  f32x4 acc[4][4] = {};
  int cur = 0;                                        // = t % 3

  for (int t = 0; t < nk; ++t) {
    if (t < nk - 1) asm volatile("s_waitcnt vmcnt(4)" ::: "memory");
    else            asm volatile("s_waitcnt vmcnt(0)" ::: "memory");
    __builtin_amdgcn_s_barrier();                     // tile t fully landed; t-1 reads done
    __builtin_amdgcn_sched_barrier(0);

    if (t + 2 < nk) {                                 // refill buffer freed at t-1
      int sb = cur + 2; if (sb >= 3) sb -= 3;         // (t+2) % 3
      stage(sb, t + 2);
    }

    const unsigned short* lA = lds + cur * BUF;
    const unsigned short* lB = lA + BM * BK;
    u16x8 af[4], bg[4];
    #pragma unroll
    for (int i = 0; i < 4; i++) af[i] = *(const u16x8*)&lA[(wm + i*16 + fr) * BK + fq * 8];
    #pragma unroll
    for (int j = 0; j < 4; j++) bg[j] = *(const u16x8*)&lB[(wn + j*16 + fr) * BK + fq * 8];

    #pragma unroll
    for (int i = 0; i < 4; i++)
      #pragma unroll
      for (int j = 0; j < 4; j++)
        acc[i][j] = __builtin_amdgcn_mfma_f32_16x16x32_bf16(
            __builtin_bit_cast(bf16x8, af[i]),
            __builtin_bit_cast(bf16x8, bg[j]),
            acc[i][j], 0, 0, 0);
    cur = (cur == 2) ? 0 : cur + 1;
  }

  #pragma unroll
  for (int i = 0; i < 4; i++)
    #pragma unroll
    for (int j = 0; j < 4; j++)
      #pragma unroll
      for (int r = 0; r < 4; r++) {
        int row = bm0 + wm + i*16 + fq*4 + r;
        int col = bn0 + wn + j*16 + fr;
        if (row < M && col < N) {
          float v2 = acc[i][j][r];
          if constexpr (EPI == 0) {
            Cf[(size_t)row * N + col] = v2 + (bias ? bias[col] : 0.0f);
          } else if constexpr (EPI == 1) {
            atomicAdd(&Cf[(size_t)row * N + col], v2);
          } else {
            Cbf[(size_t)row * N + col] = f2bf(tanhf(v2 + bias[col]));
          }
        }
      }
}

// ---------- cvtpad helper: fp32 [rows][scols] -> bf16 [rows][dcols], zero-padded ------
static __device__ __forceinline__ void cvtpad_body(
    const float* __restrict__ src, unsigned short* __restrict__ dst,
    int rows, int scols, int dcols, int i8)
{
  int c8 = dcols / 8;
  if (i8 >= rows * c8) return;
  int r = i8 / c8, c0 = (i8 % c8) * 8;
  const float* s = src + (size_t)r * scols;
  u16x8 o;
  #pragma unroll
  for (int e = 0; e < 8; e++) { int c = c0 + e; o[e] = (c < scols) ? f2bf(s[c]) : (unsigned short)0; }
  *(u16x8*)(dst + (size_t)r * dcols + c0) = o;
}

// ---------- merged prep: cvt (weights->bf16) ∥ ynorm ∥ cvtpad(embed) ∥ cvtpad(Wi) ----
// r19 change: cvt branch uses WAVE-COOPERATIVE INTERLEAVED access. Old pattern gave
// each lane a contiguous 64B chunk -> every load instruction had lanes at stride 64B
// (64 cache-line requests/instr, 4x the ideal request rate). New: each wave converts
// a 1024-float unit; lane loads q[lane], q[lane+64], q[lane+128], q[lane+192] (each
// instruction = 1KB contiguous) and stores 4x ushort4 (512B contiguous). All four
// weight segments are exact multiples of 1024 floats (40768 units total).
__global__ __launch_bounds__(256) void prep_kernel(
    const float* __restrict__ We1, unsigned short* __restrict__ We1b,
    const float* __restrict__ Wd2, unsigned short* __restrict__ Wd2b,
    const float* __restrict__ We2, unsigned short* __restrict__ We2b,
    const float* __restrict__ Wd1, unsigned short* __restrict__ Wd1b,
    const float* __restrict__ embed, unsigned short* __restrict__ embedb,
    const float* __restrict__ Wi, unsigned short* __restrict__ Wib,
    const float* __restrict__ x, const float* __restrict__ dm,
    unsigned short* __restrict__ y, float* __restrict__ ninv)
{
  constexpr int D0 = 20000, H = 1024, L = 256, V = 3356, E = 1128, Ep = 1152;
  constexpr int n0 = H * D0, n1 = D0 * H, n2 = 2 * L * H, n3 = H * L;
  constexpr int CVT_B = 2048, YN_B = 512;
  constexpr int PE_B = (V * (Ep / 8) + 255) / 256;     // 1888
  const int bb = blockIdx.x, tid = threadIdx.x;

  if (bb < CVT_B) {
    constexpr int UN0 = n0 / 1024, UN1 = n1 / 1024, UN2 = n2 / 1024;
    constexpr int NUNITS = (n0 + n1 + n2 + n3) / 1024;  // 40768
    const int lane = tid & 63;
    const int wv = bb * 4 + (tid >> 6);
    const int nwaves = CVT_B * 4;
    for (int u = wv; u < NUNITS; u += nwaves) {
      int i = u;
      const float* s; unsigned short* d;
      if (i < UN0)               { s = We1; d = We1b; }
      else if ((i -= UN0) < UN1) { s = Wd2; d = Wd2b; }
      else if ((i -= UN1) < UN2) { s = We2; d = We2b; }
      else                       { i -= UN2; s = Wd1; d = Wd1b; }
      const f32x4* q = (const f32x4*)(s + (size_t)i * 1024);
      ushort4*     o = (ushort4*)(d + (size_t)i * 1024);
      f32x4 a0 = q[lane], a1 = q[lane + 64], a2 = q[lane + 128], a3 = q[lane + 192];
      o[lane]       = cvt4h(a0);
      o[lane + 64]  = cvt4h(a1);
      o[lane + 128] = cvt4h(a2);
      o[lane + 192] = cvt4h(a3);
    }
  } else if (bb < CVT_B + YN_B) {
    const int b = bb - CVT_B;
    const float4* x4 = (const float4*)(x + (size_t)b * D0);
    const float4* d4 = (const float4*)(dm + (size_t)b * D0);
    ushort4* y4 = (ushort4*)(y + (size_t)b * D0);
    const int n4 = D0 / 4;
    float ss = 0.f;
    for (int i = tid; i < n4; i += 256) {
      float4 xv = x4[i], dv = d4[i];
      ss += xv.x*xv.x + xv.y*xv.y + xv.z*xv.z + xv.w*xv.w;
      ushort4 ov;
      ov.x = f2bf(xv.x*dv.x); ov.y = f2bf(xv.y*dv.y);
      ov.z = f2bf(xv.z*dv.z); ov.w = f2bf(xv.w*dv.w);
      y4[i] = ov;
    }
    #pragma unroll
    for (int off = 32; off > 0; off >>= 1) ss += __shfl_down(ss, off);
    __shared__ float wsum[4];
    if ((tid & 63) == 0) wsum[tid >> 6] = ss;
    __syncthreads();
    if (tid == 0) {
      float t = wsum[0] + wsum[1] + wsum[2] + wsum[3];
      ninv[b] = 1.0f / fmaxf(sqrtf(t), 1e-12f);
    }
  } else if (bb < CVT_B + YN_B + PE_B) {
    cvtpad_body(embed, embedb, V, E, Ep, (bb - (CVT_B + YN_B)) * 256 + tid);
  } else {
    cvtpad_body(Wi, Wib, L, E, Ep, (bb - (CVT_B + YN_B + PE_B)) * 256 + tid);
  }
}

// ---------------- remaining elementwise / reduction kernels ----------------
__global__ __launch_bounds__(256) void stats_kernel(
    const float* __restrict__ proj, const int* __restrict__ ids,
    const float* __restrict__ bi, const float* __restrict__ eps,
    float* __restrict__ prior, int T)
{
  const int b = blockIdx.x, l = threadIdx.x;
  __shared__ int sid[256];
  if (l < T) sid[l] = ids[b * T + l];
  __syncthreads();
  float s1 = 0.f, s2 = 0.f;
  #pragma unroll 4
  for (int t = 0; t < T; t++) {
    float p = proj[(size_t)sid[t] * 256 + l];
    s1 += p; s2 += p * p;
  }
  float var = fmaxf((s2 - s1 * s1 / (float)T) / (float)(T - 1), 0.f);
  float dev = sqrtf(var);
  float mean = s1 / (float)T + bi[l];
  prior[b * 256 + l] = mean + sqrtf(dev) * eps[b * 256 + l];
}

__global__ __launch_bounds__(256) void epi1_kernel(
    const float* __restrict__ C1, const float* __restrict__ ninv,
    const float* __restrict__ be1, unsigned short* __restrict__ h)
{
  int i = blockIdx.x * 256 + threadIdx.x;
  int b = i >> 10, n = i & 1023;
  h[i] = f2bf(tanhf(ninv[b] * C1[i] + be1[n]));
}

__global__ __launch_bounds__(256) void z_kernel(
    const float* __restrict__ gp, const float* __restrict__ prior,
    const float* __restrict__ be2,
    float* __restrict__ out_mu, float* __restrict__ out_lv,
    unsigned short* __restrict__ z)
{
  int i = blockIdx.x * 256 + threadIdx.x;
  int b = i >> 8, l = i & 255;
  float mu = gp[b * 512 + l]       + be2[l];
  float lv = gp[b * 512 + 256 + l] + be2[256 + l];
  out_mu[i] = mu;
  out_lv[i] = lv;
  z[i] = f2bf(prior[i] * expf(0.5f * lv) + mu);
}

extern "C" void kernel_launch(void* const* d_in, const int* in_sizes, int n_in,
                              void* d_out, int out_size, void* d_ws, size_t ws_size,
                              hipStream_t stream)
{
  const float* x     = (const float*)d_in[0];
  const int*   ids   = (const int*)  d_in[1];
  const float* embed = (const float*)d_in[2];
  const float* Wi    = (const float*)d_in[3];
  const float* bi    = (const float*)d_in[4];
  const float* We1   = (const float*)d_in[5];
  const float* be1   = (const float*)d_in[6];
  const float* We2   = (const float*)d_in[7];
  const float* be2   = (const float*)d_in[8];
  const float* Wd1   = (const float*)d_in[9];
  const float* bd1   = (const float*)d_in[10];
  const float* Wd2   = (const float*)d_in[11];
  const float* bd2   = (const float*)d_in[12];
  const float* dm    = (const float*)d_in[13];
  const float* eps   = (const float*)d_in[14];

  constexpr int B = 512, T = 200, V = 3356, E = 1128, Ep = 1152, D0 = 20000, H = 1024, L = 256;

  char* w = (char*)d_ws;
  auto carve = [&](size_t bytes) { char* p = w; w += (bytes + 255) & ~(size_t)255; return p; };
  unsigned short* We1b  = (unsigned short*)carve((size_t)H * D0 * 2);   // 41 MB
  unsigned short* Wd2b  = (unsigned short*)carve((size_t)D0 * H * 2);   // 41 MB
  unsigned short* We2b  = (unsigned short*)carve((size_t)2 * L * H * 2);
  unsigned short* Wd1b  = (unsigned short*)carve((size_t)H * L * 2);
  unsigned short* embedb= (unsigned short*)carve((size_t)V * Ep * 2);   // 7.7 MB
  unsigned short* Wib   = (unsigned short*)carve((size_t)L * Ep * 2);
  float*          proj  = (float*)         carve((size_t)V * L * 4);    // 3.4 MB
  unsigned short* y     = (unsigned short*)carve((size_t)B * D0 * 2);   // 20.5 MB
  float*          C1    = (float*)         carve((size_t)B * H * 4);
  unsigned short* h     = (unsigned short*)carve((size_t)B * H * 2);
  float*          gp    = (float*)         carve((size_t)B * 2 * L * 4);
  float*          prior = (float*)         carve((size_t)B * L * 4);
  unsigned short* z     = (unsigned short*)carve((size_t)B * L * 2);
  unsigned short* hd    = (unsigned short*)carve((size_t)B * H * 2);
  float*          ninv  = (float*)         carve((size_t)B * 4);

  float* out_recon = (float*)d_out;
  float* out_mu    = out_recon + (size_t)B * D0;
  float* out_lv    = out_mu + (size_t)B * L;

  // merged prep: weights->bf16 (interleaved) ∥ y=bf16(x*dm)+ninv ∥ embed/Wi pad-convert
  {
    constexpr int CVT_B = 2048, YN_B = 512;
    constexpr int PE_B = (V * (Ep / 8) + 255) / 256;    // 1888
    constexpr int PW_B = (L * (Ep / 8) + 255) / 256;    // 144
    prep_kernel<<<CVT_B + YN_B + PE_B + PW_B, 256, 0, stream>>>(
        We1, We1b, Wd2, Wd2b, We2, We2b, Wd1, Wd1b,
        embed, embedb, Wi, Wib, x, dm, y, ninv);
  }

  // proj = embedb @ Wib^T  (M=3356, N=256, K=1152), split-K=4
  hipMemsetAsync(proj, 0, (size_t)V * L * 4, stream);
  gemm_bf<1><<<dim3(2, 27, 4), 256, 0, stream>>>(
      embedb, Wib, nullptr, proj, nullptr, V, L, Ep, 288);
  // prior from gathered stats (adds bi)
  stats_kernel<<<B, 256, 0, stream>>>(proj, ids, bi, eps, prior, T);

  // GEMM1: C1 = y @ We1b^T  (M=512, N=1024, K=20000), split-K=25
  hipMemsetAsync(C1, 0, (size_t)B * H * 4, stream);
  gemm_bf<1><<<dim3(8, 4, 25), 256, 0, stream>>>(
      y, We1b, nullptr, C1, nullptr, B, H, D0, 800);
  // h = tanh(ninv*C1 + be1)
  epi1_kernel<<<(B * H) / 256, 256, 0, stream>>>(C1, ninv, be1, h);

  // gparams = h @ We2b^T (+be2 in z_kernel)  (M=512, N=512, K=1024), split-K=4
  hipMemsetAsync(gp, 0, (size_t)B * 2 * L * 4, stream);
  gemm_bf<1><<<dim3(4, 4, 4), 256, 0, stream>>>(
      h, We2b, nullptr, gp, nullptr, B, 2 * L, H, 256);
  // mu/logvar out, z
  z_kernel<<<(B * L) / 256, 256, 0, stream>>>(gp, prior, be2, out_mu, out_lv, z);

  // hd = tanh(z @ Wd1b^T + bd1)  (M=512, N=1024, K=256)
  gemm_bf<2><<<dim3(8, 4, 1), 256, 0, stream>>>(
      z, Wd1b, bd1, nullptr, hd, B, H, L, 256);
  // recon = hd @ Wd2b^T + bd2   (M=512, N=20000, K=1024)
  gemm_bf<0><<<dim3(157, 4, 1), 256, 0, stream>>>(
      hd, Wd2b, bd2, out_recon, nullptr, B, D0, H, 1024);
}